// Round 16
// baseline (33.356 us; speedup 1.0000x reference)
//
#include <hip/hip_runtime.h>

typedef float vf4 __attribute__((ext_vector_type(4)));

#define BATCH  8192
#define GROUPS 512
#define OUT_D  8
#define GCH    32                 // groups per block
#define NCH    (GROUPS / GCH)     // 16 chunks
#define RT     64                 // batch rows per block (16 per wave)
#define RW     16                 // rows per wave
#define PQ     54                 // float4 per group in P (27*8 floats)
#define LQ     55                 // float4 per group in LDS (pad: 55%8=7 spreads bank-quads)

// Final kernel (= R10, the best verified configuration, 33.4us):
//  - param gathers on the LDS pipe (the R8 breakthrough: the TA/L1 pipe
//    serializing 25M divergent 16B gathers was the original floor)
//  - pair-split lanes: lane l covers half (l&1) of group (l>>1); a lane
//    pair reads adjacent 16B halves of one 32B param row
//  - 1KB-contiguous nontemporal stores (WRITE_SIZE exactly ideal)
//  - X ingress batched: 48 dwords issued as one burst before compute
//  - 27.5KB LDS -> 5 blocks/CU; co-resident blocks share one param chunk
__global__ __launch_bounds__(256) void hoact_kernel(
    const float* __restrict__ X,
    const float* __restrict__ P,
    float* __restrict__ out)
{
    __shared__ vf4 lp[GCH * LQ];       // 27.5 KB

    const int chunk = blockIdx.x % NCH;   // co-resident blocks share the chunk
    const int rt    = blockIdx.x / NCH;

    const int tid  = threadIdx.x;
    const int lane = tid & 63;
    const int w    = tid >> 6;
    const int gsub = lane >> 1;        // group within chunk 0..31
    const int h    = lane & 1;         // which 16B half of the param row

    // ---- stage params for this chunk: linear L2 read, padded LDS write ----
    const vf4* P4 = (const vf4*)P + (size_t)chunk * (GCH * PQ);
    #pragma unroll
    for (int k = 0; k < 7; ++k) {
        int m = tid + 256 * k;         // 0..1791, need < 1728
        if (m < GCH * PQ) {
            int gq = m / PQ;
            int iq = m - gq * PQ;
            lp[gq * LQ + iq] = P4[m];
        }
    }

    // ---- batched X load: 48 dwords (16 rows x 3), all independent ----
    const int g = chunk * GCH + gsub;
    const int row0 = rt * RT + w * RW;
    const float* xcol = X + (size_t)g * 3 + (size_t)row0 * (GROUPS * 3);
    float xv[RW][3];
    #pragma unroll
    for (int it = 0; it < RW; ++it) {
        const float* xp = xcol + (size_t)it * (GROUPS * 3);
        xv[it][0] = xp[0];
        xv[it][1] = xp[1];
        xv[it][2] = xp[2];
    }

    __syncthreads();

    vf4* outb = (vf4*)out + (size_t)chunk * (GCH * OUT_D / 4) + lane
              + (size_t)row0 * (GROUPS * OUT_D / 4);
    const size_t row_u = GROUPS * OUT_D / 4;     // 1024 units per out row
    const int base = gsub * LQ + h;

    #pragma unroll
    for (int it = 0; it < RW; ++it) {
        float x0 = xv[it][0], x1 = xv[it][1], x2 = xv[it][2];

        float b0 = fabsf(x0), b1 = fabsf(x1), b2 = fabsf(x2);
        int t0 = (x0 >= 0.f) ? 1 : -1;
        int t1 = (x1 >= 0.f) ? 3 : -3;
        int t2 = (x2 >= 0.f) ? 9 : -9;
        // sort ascending by |x| (ties don't affect the result)
        if (b0 > b1) { float tb=b0; b0=b1; b1=tb; int tt=t0; t0=t1; t1=tt; }
        if (b1 > b2) { float tb=b1; b1=b2; b2=tb; int tt=t1; t1=t2; t2=tt; }
        if (b0 > b1) { float tb=b0; b0=b1; b1=tb; int tt=t0; t0=t1; t1=tt; }
        int i2 = t2 + 13;
        int i1 = t1 + t2 + 13;
        int i0 = t0 + t1 + t2 + 13;
        float c0 = b0;
        float c1 = b1 - b0;
        float c2 = b2 - b1;

        // LDS gathers: unit = gsub*55 + h + idx*2 (pair reads one 32B row)
        vf4 q0 = lp[base + i0 * 2];
        vf4 q1 = lp[base + i1 * 2];
        vf4 q2 = lp[base + i2 * 2];

        vf4 r = c0 * q0 + c1 * q1 + c2 * q2;

        // 64 lanes -> 64 consecutive float4 units: 1KB contiguous store
        __builtin_nontemporal_store(r, outb + (size_t)it * row_u);
    }
}

extern "C" void kernel_launch(void* const* d_in, const int* in_sizes, int n_in,
                              void* d_out, int out_size, void* d_ws, size_t ws_size,
                              hipStream_t stream) {
    const float* X = (const float*)d_in[0];
    const float* P = (const float*)d_in[1];
    float* out = (float*)d_out;

    const int grid = (BATCH / RT) * NCH;   // 128 * 16 = 2048
    hoact_kernel<<<grid, 256, 0, stream>>>(X, P, out);
}